// Round 23
// baseline (319.823 us; speedup 1.0000x reference)
//
#include <hip/hip_runtime.h>
#include <hip/hip_bf16.h>
#include <math.h>

// Problem constants
#define TOKS 16384   // B*N
#define DDIM 256
#define KC   8192

static constexpr float EMA   = 0.99f;
static constexpr float ONE_M = (float)(1.0 - 0.99);
static constexpr float EPSF  = 1e-5f;
static constexpr float KEPS  = (float)(8192 * 1e-5);

// screen params
#define CTILE  32
#define CAP    128       // empirical max n at sample=2048 is <=120 (round 18)
#define DELTA  2.0e-4f   // containment window (worst-case need ~5.6e-5)

// ---------------- ws layout (float index) ----------------
#define SCAL_OFF  0          // 16
#define UCNT_OFF  16         // 8192 (uint)  per-code token count
#define FILL_OFF  8208       // 8192 (uint)  scatter fill cursor
#define CNT_OFF   16400      // 16384 (uint) per-token candidate count
#define GMX_OFF   32784      // 16384 (uint) sample max keys
// ^ [0, 49168) zeroed by ONE memset
#define AN_OFF    49168      // 16384
#define BN_OFF    65552      // 8192
#define IDXI_OFF  73744      // 16384 (int)
#define BASE_OFF  90128      // 8192 (uint)
#define TOK_OFF   98320      // 16384 ushort = 8192 floats
#define EB_OFF    106512     // 2M ushort = 1048576 floats
#define LISTS_OFF 1155088    // 16384*128 ushort = 1048576 floats
// end = 2203664 floats = 8.41 MB (< 8.44 MB proven in round 5)
// zb (bf16 z) lives in o0's first half (scratch until rescore overwrites)

typedef __attribute__((ext_vector_type(8))) short bf16x8;
typedef __attribute__((ext_vector_type(4))) short bf16x4;
typedef __attribute__((ext_vector_type(4))) float f32x4;

static __device__ inline short f2b(float f) {
  __hip_bfloat16 h = __float2bfloat16(f);
  return *reinterpret_cast<short*>(&h);
}
static __device__ inline unsigned int fkey(float f) {
  unsigned int b = __float_as_uint(f);
  return (b & 0x80000000u) ? ~b : (b | 0x80000000u);
}
static __device__ inline float funkey(unsigned int k) {
  unsigned int b = (k & 0x80000000u) ? (k & 0x7FFFFFFFu) : ~k;
  return __uint_as_float(b);
}

// ---------------- fused: {emb,z} -> bf16 copy + row sqnorms ----------------
__global__ __launch_bounds__(256) void k_conv(const float* __restrict__ e,
                                              const float* __restrict__ z,
                                              unsigned short* __restrict__ eb,
                                              unsigned short* __restrict__ zb,
                                              float* __restrict__ bn,
                                              float* __restrict__ an) {
  const int lane = threadIdx.x & 63;
  const int row = blockIdx.x * 4 + (threadIdx.x >> 6);
  const bool isE = row < KC;
  const float* src = isE ? e : z;
  unsigned short* dst = isE ? eb : zb;
  float* nrm = isE ? bn : an;
  const int r = isE ? row : row - KC;
  const float4 v = *reinterpret_cast<const float4*>(src + (size_t)r * DDIM + lane * 4);
  bf16x4 b;
  b[0] = f2b(v.x); b[1] = f2b(v.y); b[2] = f2b(v.z); b[3] = f2b(v.w);
  *reinterpret_cast<bf16x4*>(dst + (size_t)r * DDIM + lane * 4) = b;
  float s = v.x * v.x + v.y * v.y + v.z * v.z + v.w * v.w;
#pragma unroll
  for (int d = 32; d; d >>= 1) s += __shfl_down(s, d);
  if (lane == 0) nrm[r] = s;
}

// ---------------- bf16 MFMA screen (round-20/22 proven rf=2 form) ----------------
template<bool COLLECT>
__global__ __launch_bounds__(256, 4) void k_screen(
    const unsigned short* __restrict__ zb, const unsigned short* __restrict__ eb,
    unsigned int* __restrict__ gmx,
    unsigned int* __restrict__ cnt, unsigned short* __restrict__ lists) {
  constexpr int CHUNKC = COLLECT ? 1024 : 256;
  constexpr int NITC = CHUNKC / CTILE;
  __shared__ unsigned short Bt[2][CTILE * 256];   // 2 x 16KB

  const int tid = threadIdx.x;
  const int lane = tid & 63;
  const int w = tid >> 6;
  const int t0 = blockIdx.x * 128;
  const int k0 = blockIdx.y * CHUNKC;

  bf16x8 a[2][8];
  {
    const int rlo = lane & 15;
    const int khi = (lane >> 4) * 8;
#pragma unroll
    for (int rf = 0; rf < 2; ++rf) {
      const unsigned short* zr =
          zb + (size_t)(t0 + w * 32 + rf * 16 + rlo) * DDIM + khi;
#pragma unroll
      for (int kk = 0; kk < 8; ++kk)
        a[rf][kk] = *reinterpret_cast<const bf16x8*>(zr + kk * 32);
    }
  }

  float tr[2][4];
  float rm[2][4];
#pragma unroll
  for (int rf = 0; rf < 2; ++rf)
#pragma unroll
    for (int r = 0; r < 4; ++r) {
      rm[rf][r] = -1e30f;
      if (COLLECT)
        tr[rf][r] = funkey(gmx[t0 + w * 32 + rf * 16 + (lane >> 4) * 4 + r]) - DELTA;
    }

  const char* ebB = reinterpret_cast<const char*>(eb);
  const int sc = tid >> 3;
  const int ss = tid & 7;
  const int swz = (sc & 7) << 4;

  {
    const size_t gb = (size_t)(k0 + sc) * 512 + ss * 16;
    char* dst = reinterpret_cast<char*>(&Bt[0][0]) + sc * 512;
#pragma unroll
    for (int q = 0; q < 4; ++q) {
      const uint4 g = *reinterpret_cast<const uint4*>(ebB + gb + q * 128);
      *reinterpret_cast<uint4*>(dst + ((ss * 16 + q * 128) ^ swz)) = g;
    }
  }
  __syncthreads();

  const int rdlo = lane & 15;
  const int rdhi = (lane >> 4) * 16;
  uint4 g[4];

  for (int ct = 0; ct < NITC; ++ct) {
    if (ct + 1 < NITC) {
      const size_t gb = (size_t)(k0 + (ct + 1) * CTILE + sc) * 512 + ss * 16;
#pragma unroll
      for (int q = 0; q < 4; ++q)
        g[q] = *reinterpret_cast<const uint4*>(ebB + gb + q * 128);
    }

    f32x4 acc[2][2];
#pragma unroll
    for (int rf = 0; rf < 2; ++rf)
#pragma unroll
      for (int cf = 0; cf < 2; ++cf) acc[rf][cf] = (f32x4){0.f, 0.f, 0.f, 0.f};

    const char* buf = reinterpret_cast<const char*>(&Bt[ct & 1][0]);
#pragma unroll
    for (int kk = 0; kk < 8; ++kk) {
      const int off = (kk * 64 + rdhi) ^ ((rdlo & 7) << 4);
      const bf16x8 b0 = *reinterpret_cast<const bf16x8*>(buf + rdlo * 512 + off);
      const bf16x8 b1 = *reinterpret_cast<const bf16x8*>(buf + (16 + rdlo) * 512 + off);
      acc[0][0] = __builtin_amdgcn_mfma_f32_16x16x32_bf16(a[0][kk], b0, acc[0][0], 0, 0, 0);
      acc[1][0] = __builtin_amdgcn_mfma_f32_16x16x32_bf16(a[1][kk], b0, acc[1][0], 0, 0, 0);
      acc[0][1] = __builtin_amdgcn_mfma_f32_16x16x32_bf16(a[0][kk], b1, acc[0][1], 0, 0, 0);
      acc[1][1] = __builtin_amdgcn_mfma_f32_16x16x32_bf16(a[1][kk], b1, acc[1][1], 0, 0, 0);
    }

    if (!COLLECT) {
#pragma unroll
      for (int rf = 0; rf < 2; ++rf)
#pragma unroll
        for (int r = 0; r < 4; ++r)
          rm[rf][r] = fmaxf(rm[rf][r], fmaxf(acc[rf][0][r], acc[rf][1][r]));
    } else {
      const int kb = k0 + ct * CTILE;
#pragma unroll
      for (int rf = 0; rf < 2; ++rf) {
#pragma unroll
        for (int r = 0; r < 4; ++r) {
          const float th = tr[rf][r];
          if (acc[rf][0][r] >= th || acc[rf][1][r] >= th) {
            const int t = t0 + w * 32 + rf * 16 + (lane >> 4) * 4 + r;
            if (acc[rf][0][r] >= th) {
              const unsigned int o_ = atomicAdd(&cnt[t], 1u);
              if (o_ < CAP) lists[(size_t)t * CAP + o_] = (unsigned short)(kb + rdlo);
            }
            if (acc[rf][1][r] >= th) {
              const unsigned int o_ = atomicAdd(&cnt[t], 1u);
              if (o_ < CAP) lists[(size_t)t * CAP + o_] = (unsigned short)(kb + 16 + rdlo);
            }
          }
        }
      }
    }

    if (ct + 1 < NITC) {
      char* dst = reinterpret_cast<char*>(&Bt[(ct + 1) & 1][0]) + sc * 512;
#pragma unroll
      for (int q = 0; q < 4; ++q)
        *reinterpret_cast<uint4*>(dst + ((ss * 16 + q * 128) ^ swz)) = g[q];
    }
    __syncthreads();
  }

  if (!COLLECT) {
#pragma unroll
    for (int rf = 0; rf < 2; ++rf) {
#pragma unroll
      for (int r = 0; r < 4; ++r) {
        float v = rm[rf][r];
#pragma unroll
        for (int o = 1; o <= 8; o <<= 1) v = fmaxf(v, __shfl_xor(v, o));
        if ((lane & 15) == 0) {
          const int t = t0 + w * 32 + rf * 16 + (lane >> 4) * 4 + r;
          atomicMax(&gmx[t], fkey(v));
        }
      }
    }
  }
}

// ---------------- rescore + o0/loss + per-code count (NO o8 scatter) ----------------
__global__ __launch_bounds__(256) void k_rescore(
    const float* __restrict__ z, const float* __restrict__ emb,
    const float* __restrict__ an, const float* __restrict__ bn,
    const unsigned int* __restrict__ cnt, const unsigned short* __restrict__ lists,
    float* __restrict__ out_idx, int* __restrict__ idxi,
    float* __restrict__ o0, unsigned int* __restrict__ ucnt,
    float* __restrict__ scal) {
  const int w = threadIdx.x >> 6;
  const int lane = threadIdx.x & 63;
  const int t = blockIdx.x * 4 + w;

  const float4 z4 = *reinterpret_cast<const float4*>(z + (size_t)t * DDIM + lane * 4);
  const unsigned int nraw = cnt[t];
  const float aN = an[t];
  float bd = 3.4e38f;
  int bk = 0x7fffffff;

  if (nraw <= CAP) {
    const int n = (int)nraw;
    for (int c = 0; c < n; ++c) {
      const int k = (int)lists[(size_t)t * CAP + c];   // broadcast load
      const float4 e4 = *reinterpret_cast<const float4*>(emb + (size_t)k * DDIM + lane * 4);
      float p = z4.x * e4.x + z4.y * e4.y + z4.z * e4.z + z4.w * e4.w;
#pragma unroll
      for (int o = 32; o; o >>= 1) p += __shfl_xor(p, o);
      const float d = __fsub_rn(__fadd_rn(aN, bn[k]), __fmul_rn(2.0f, p));
      if (d < bd || (d == bd && k < bk)) { bd = d; bk = k; }
    }
  } else {
    // overflow fallback: cooperative full scan, 4-way unrolled (pipelined)
    for (int kb = 0; kb < KC; kb += 4) {
      float p0, p1, p2, p3;
      {
        const float4 e0 = *reinterpret_cast<const float4*>(emb + (size_t)(kb + 0) * DDIM + lane * 4);
        const float4 e1 = *reinterpret_cast<const float4*>(emb + (size_t)(kb + 1) * DDIM + lane * 4);
        const float4 e2 = *reinterpret_cast<const float4*>(emb + (size_t)(kb + 2) * DDIM + lane * 4);
        const float4 e3 = *reinterpret_cast<const float4*>(emb + (size_t)(kb + 3) * DDIM + lane * 4);
        p0 = z4.x * e0.x + z4.y * e0.y + z4.z * e0.z + z4.w * e0.w;
        p1 = z4.x * e1.x + z4.y * e1.y + z4.z * e1.z + z4.w * e1.w;
        p2 = z4.x * e2.x + z4.y * e2.y + z4.z * e2.z + z4.w * e2.w;
        p3 = z4.x * e3.x + z4.y * e3.y + z4.z * e3.z + z4.w * e3.w;
      }
#pragma unroll
      for (int o = 32; o; o >>= 1) {
        p0 += __shfl_xor(p0, o);
        p1 += __shfl_xor(p1, o);
        p2 += __shfl_xor(p2, o);
        p3 += __shfl_xor(p3, o);
      }
      const float d0 = __fsub_rn(__fadd_rn(aN, bn[kb + 0]), __fmul_rn(2.0f, p0));
      const float d1 = __fsub_rn(__fadd_rn(aN, bn[kb + 1]), __fmul_rn(2.0f, p1));
      const float d2 = __fsub_rn(__fadd_rn(aN, bn[kb + 2]), __fmul_rn(2.0f, p2));
      const float d3 = __fsub_rn(__fadd_rn(aN, bn[kb + 3]), __fmul_rn(2.0f, p3));
      if (d0 < bd) { bd = d0; bk = kb + 0; }
      if (d1 < bd) { bd = d1; bk = kb + 1; }
      if (d2 < bd) { bd = d2; bk = kb + 2; }
      if (d3 < bd) { bd = d3; bk = kb + 3; }
    }
  }

  if (lane == 0) {
    out_idx[t] = (float)bk;
    idxi[t] = bk;
    atomicAdd(&ucnt[bk], 1u);
  }

  // ---- o0 + loss epilogue (bk identical across lanes) ----
  const float4 ev = *reinterpret_cast<const float4*>(emb + (size_t)bk * DDIM + lane * 4);
  float4 o;
  o.x = __fadd_rn(z4.x, __fsub_rn(ev.x, z4.x));
  o.y = __fadd_rn(z4.y, __fsub_rn(ev.y, z4.y));
  o.z = __fadd_rn(z4.z, __fsub_rn(ev.z, z4.z));
  o.w = __fadd_rn(z4.w, __fsub_rn(ev.w, z4.w));
  *reinterpret_cast<float4*>(o0 + (size_t)t * DDIM + lane * 4) = o;
  const float dx = __fsub_rn(z4.x, ev.x);
  const float dy = __fsub_rn(z4.y, ev.y);
  const float dz = __fsub_rn(z4.z, ev.z);
  const float dw = __fsub_rn(z4.w, ev.w);
  float lsum = dx * dx + dy * dy + dz * dz + dw * dw;
#pragma unroll
  for (int o_ = 32; o_; o_ >>= 1) lsum += __shfl_down(lsum, o_);
  __shared__ float wsum[4];
  if (lane == 0) wsum[w] = lsum;
  __syncthreads();
  if (threadIdx.x == 0)
    atomicAdd(scal + 0, wsum[0] + wsum[1] + wsum[2] + wsum[3]);
}

// ---------------- exclusive prefix scan of per-code counts (1 block) ----------------
__global__ __launch_bounds__(256) void k_scan(const unsigned int* __restrict__ ucnt,
                                              unsigned int* __restrict__ base) {
  __shared__ unsigned int part[256];
  const int tid = threadIdx.x;
  unsigned int loc[32];
  unsigned int s = 0;
#pragma unroll
  for (int i = 0; i < 32; ++i) { loc[i] = s; s += ucnt[tid * 32 + i]; }
  part[tid] = s;
  __syncthreads();
  if (tid == 0) {
    unsigned int run = 0;
    for (int j = 0; j < 256; ++j) { const unsigned int v = part[j]; part[j] = run; run += v; }
  }
  __syncthreads();
  const unsigned int b = part[tid];
#pragma unroll
  for (int i = 0; i < 32; ++i) base[tid * 32 + i] = b + loc[i];
}

// ---------------- scatter token ids into per-code segments ----------------
__global__ __launch_bounds__(256) void k_scatter(const int* __restrict__ idxi,
                                                 const unsigned int* __restrict__ base,
                                                 unsigned int* __restrict__ fill,
                                                 unsigned short* __restrict__ tok) {
  const int t = blockIdx.x * 256 + threadIdx.x;
  const int k = idxi[t];
  const unsigned int p = atomicAdd(&fill[k], 1u);
  tok[base[k] + p] = (unsigned short)t;
}

// ---------------- gather: o8 = EMA*ema_w + ONE_M*sum(z) ; fused stats ----------------
// One wave per code; coalesced float4 row loads; single non-atomic o8 write.
__global__ __launch_bounds__(256) void k_gather(
    const float* __restrict__ z, const float* __restrict__ ema_w,
    const unsigned int* __restrict__ ucnt, const unsigned int* __restrict__ base,
    const unsigned short* __restrict__ tok,
    const float* __restrict__ ecs_in, const float* __restrict__ cu_in,
    float* __restrict__ o8, float* __restrict__ o7, float* __restrict__ o9,
    float* __restrict__ scal) {
  const int w = threadIdx.x >> 6;
  const int lane = threadIdx.x & 63;
  const int k = blockIdx.x * 4 + w;
  const unsigned int c = ucnt[k];
  const unsigned int b = base[k];

  float4 sum = {0.f, 0.f, 0.f, 0.f};
  for (unsigned int i = 0; i < c; ++i) {
    const int t = (int)tok[b + i];
    const float4 zv = *reinterpret_cast<const float4*>(z + (size_t)t * DDIM + lane * 4);
    sum.x += zv.x; sum.y += zv.y; sum.z += zv.z; sum.w += zv.w;
  }
  const float4 ew = *reinterpret_cast<const float4*>(ema_w + (size_t)k * DDIM + lane * 4);
  float4 r;
  r.x = EMA * ew.x + ONE_M * sum.x;
  r.y = EMA * ew.y + ONE_M * sum.y;
  r.z = EMA * ew.z + ONE_M * sum.z;
  r.w = EMA * ew.w + ONE_M * sum.w;
  *reinterpret_cast<float4*>(o8 + (size_t)k * DDIM + lane * 4) = r;

  // fused per-code stats
  float s0 = 0.f, s1 = 0.f, s2 = 0.f;
  if (lane == 0) {
    const float cc = (float)c;
    const float raw = EMA * ecs_in[k] + ONE_M * cc;
    o7[k] = raw;
    const float ncu = __fadd_rn(cu_in[k], cc);
    o9[k] = ncu;
    s0 = raw;
    const float p = cc * (1.0f / 16384.0f);
    s1 = p * logf(p + 1e-10f);
    s2 = ncu > 0.0f ? 1.0f : 0.0f;
  }
  __shared__ float sh0[4], sh1[4], sh2[4];
  if (lane == 0) { sh0[w] = s0; sh1[w] = s1; sh2[w] = s2; }
  __syncthreads();
  if (threadIdx.x == 0) {
    atomicAdd(scal + 1, sh0[0] + sh0[1] + sh0[2] + sh0[3]);
    atomicAdd(scal + 2, sh1[0] + sh1[1] + sh1[2] + sh1[3]);
    atomicAdd(scal + 3, sh2[0] + sh2[1] + sh2[2] + sh2[3]);
  }
}

// ---------------- fused: Laplace + emb update + scalar outputs ----------------
__global__ __launch_bounds__(256) void k_final(float* __restrict__ o7,
                                               const float* __restrict__ o8,
                                               const float* __restrict__ scal,
                                               float* __restrict__ o6,
                                               float* __restrict__ o2,
                                               float* __restrict__ o3,
                                               float* __restrict__ o4,
                                               float* __restrict__ o5) {
  const int lane = threadIdx.x & 63;
  const int k = blockIdx.x * 4 + (threadIdx.x >> 6);
  const float n = scal[1];
  const float raw = o7[k];
  const float sm = (raw + EPSF) / (n + KEPS) * n;
  if (lane == 0) o7[k] = sm;
  const float dnm = fmaxf(sm, EPSF);
  const size_t i = (size_t)k * DDIM + lane * 4;
  const float4 v = *reinterpret_cast<const float4*>(o8 + i);
  float4 r;
  r.x = v.x / dnm; r.y = v.y / dnm; r.z = v.z / dnm; r.w = v.w / dnm;
  *reinterpret_cast<float4*>(o6 + i) = r;
  if (blockIdx.x == 0 && threadIdx.x == 0) {
    const float m = scal[0] * (1.0f / 4194304.0f);
    o2[0] = 0.25f * m + m;
    o3[0] = expf(-scal[2]);
    o4[0] = scal[3] * (1.0f / 8192.0f);
    o5[0] = scal[3];
  }
}

extern "C" void kernel_launch(void* const* d_in, const int* in_sizes, int n_in,
                              void* d_out, int out_size, void* d_ws, size_t ws_size,
                              hipStream_t stream) {
  const float* z     = (const float*)d_in[0];
  const float* emb   = (const float*)d_in[1];
  const float* ecs   = (const float*)d_in[2];
  const float* ema_w = (const float*)d_in[3];
  const float* cu    = (const float*)d_in[4];

  float* out = (float*)d_out;
  float* o0 = out;
  float* o1 = o0 + 4194304;
  float* o2 = o1 + 16384;
  float* o3 = o2 + 1;
  float* o4 = o3 + 1;
  float* o5 = o4 + 1;
  float* o6 = o5 + 1;
  float* o7 = o6 + 2097152;
  float* o8 = o7 + 8192;
  float* o9 = o8 + 2097152;

  float* w    = (float*)d_ws;
  float* scal = w + SCAL_OFF;
  unsigned int* ucnt = (unsigned int*)(w + UCNT_OFF);
  unsigned int* fill = (unsigned int*)(w + FILL_OFF);
  unsigned int* cnt  = (unsigned int*)(w + CNT_OFF);
  unsigned int* gmx  = (unsigned int*)(w + GMX_OFF);
  float* an   = w + AN_OFF;
  float* bn   = w + BN_OFF;
  int*   idxi = (int*)(w + IDXI_OFF);
  unsigned int* base = (unsigned int*)(w + BASE_OFF);
  unsigned short* tok = (unsigned short*)(w + TOK_OFF);
  unsigned short* eb  = (unsigned short*)(w + EB_OFF);
  unsigned short* lists = (unsigned short*)(w + LISTS_OFF);
  // zb: bf16 copy of z in o0's first half (scratch until rescore overwrites)
  unsigned short* zb = (unsigned short*)o0;

  // one memset covers scal + ucnt + fill + cnt + gmx
  hipMemsetAsync(w, 0, (size_t)(GMX_OFF + TOKS) * sizeof(float) - 0, stream);

  k_conv<<<(KC + TOKS) / 4, 256, 0, stream>>>(emb, z, eb, zb, bn, an);

  // sample pass: codes 0..2047 (8 chunks of 256) -> gmx = per-token sample max
  k_screen<false><<<dim3(TOKS / 128, 8), 256, 0, stream>>>(zb, eb, gmx, cnt, lists);
  // collect pass: all 8192 codes (8 chunks of 1024); thr computed inline from gmx
  k_screen<true><<<dim3(TOKS / 128, 8), 256, 0, stream>>>(zb, eb, gmx, cnt, lists);

  // rescore (idx + o0 + loss + per-code counts; overwrites zb region of o0)
  k_rescore<<<TOKS / 4, 256, 0, stream>>>(z, emb, an, bn, cnt, lists,
                                          o1, idxi, o0, ucnt, scal);

  // inverted index: scan counts -> bases; scatter token ids; gather rows
  k_scan<<<1, 256, 0, stream>>>(ucnt, base);
  k_scatter<<<TOKS / 256, 256, 0, stream>>>(idxi, base, fill, tok);
  k_gather<<<KC / 4, 256, 0, stream>>>(z, ema_w, ucnt, base, tok, ecs, cu,
                                       o8, o7, o9, scal);

  k_final<<<KC / 4, 256, 0, stream>>>(o7, o8, scal, o6, o2, o3, o4, o5);
}

// Round 24
// 247.393 us; speedup vs baseline: 1.2928x; 1.2928x over previous
//
#include <hip/hip_runtime.h>
#include <hip/hip_bf16.h>
#include <math.h>

// Problem constants
#define TOKS 16384   // B*N
#define DDIM 256
#define KC   8192

static constexpr float EMA   = 0.99f;
static constexpr float ONE_M = (float)(1.0 - 0.99);
static constexpr float EPSF  = 1e-5f;
static constexpr float KEPS  = (float)(8192 * 1e-5);

// screen params
#define CTILE  32
#define CAP    128       // empirical max n at sample=2048 is <=120 (round 18)
#define DELTA  2.0e-4f   // containment window (worst-case need ~5.6e-5)

// ---------------- ws layout (float index) ----------------
#define SCAL_OFF  0          // 16
#define UCNT_OFF  16         // 8192 (uint)  per-code token count
#define FILL_OFF  8208       // 8192 (uint)  scatter fill cursor
#define CNT_OFF   16400      // 16384 (uint) per-token candidate count
#define GMX_OFF   32784      // 16384 (uint) sample max keys
// ^ [0, 49168) zeroed by ONE memset
#define AN_OFF    49168      // 16384
#define BN_OFF    65552      // 8192
#define IDXI_OFF  73744      // 16384 (int)
#define BASE_OFF  90128      // 8192 (uint)
#define TOK_OFF   98320      // 16384 ushort = 8192 floats
#define EB_OFF    106512     // 2M ushort = 1048576 floats
#define LISTS_OFF 1155088    // 16384*128 ushort = 1048576 floats
// end = 2203664 floats = 8.41 MB (< 8.44 MB proven in round 5)
// zb (bf16 z) lives in o0's first half (scratch until rescore overwrites)

typedef __attribute__((ext_vector_type(8))) short bf16x8;
typedef __attribute__((ext_vector_type(4))) short bf16x4;
typedef __attribute__((ext_vector_type(4))) float f32x4;

static __device__ inline short f2b(float f) {
  __hip_bfloat16 h = __float2bfloat16(f);
  return *reinterpret_cast<short*>(&h);
}
static __device__ inline unsigned int fkey(float f) {
  unsigned int b = __float_as_uint(f);
  return (b & 0x80000000u) ? ~b : (b | 0x80000000u);
}
static __device__ inline float funkey(unsigned int k) {
  unsigned int b = (k & 0x80000000u) ? (k & 0x7FFFFFFFu) : ~k;
  return __uint_as_float(b);
}

// ---------------- fused: {emb,z} -> bf16 copy + row sqnorms ----------------
__global__ __launch_bounds__(256) void k_conv(const float* __restrict__ e,
                                              const float* __restrict__ z,
                                              unsigned short* __restrict__ eb,
                                              unsigned short* __restrict__ zb,
                                              float* __restrict__ bn,
                                              float* __restrict__ an) {
  const int lane = threadIdx.x & 63;
  const int row = blockIdx.x * 4 + (threadIdx.x >> 6);
  const bool isE = row < KC;
  const float* src = isE ? e : z;
  unsigned short* dst = isE ? eb : zb;
  float* nrm = isE ? bn : an;
  const int r = isE ? row : row - KC;
  const float4 v = *reinterpret_cast<const float4*>(src + (size_t)r * DDIM + lane * 4);
  bf16x4 b;
  b[0] = f2b(v.x); b[1] = f2b(v.y); b[2] = f2b(v.z); b[3] = f2b(v.w);
  *reinterpret_cast<bf16x4*>(dst + (size_t)r * DDIM + lane * 4) = b;
  float s = v.x * v.x + v.y * v.y + v.z * v.z + v.w * v.w;
#pragma unroll
  for (int d = 32; d; d >>= 1) s += __shfl_down(s, d);
  if (lane == 0) nrm[r] = s;
}

// ---------------- bf16 MFMA screen (round-20/22 proven rf=2 form) ----------------
template<bool COLLECT>
__global__ __launch_bounds__(256, 4) void k_screen(
    const unsigned short* __restrict__ zb, const unsigned short* __restrict__ eb,
    unsigned int* __restrict__ gmx,
    unsigned int* __restrict__ cnt, unsigned short* __restrict__ lists) {
  constexpr int CHUNKC = COLLECT ? 1024 : 256;
  constexpr int NITC = CHUNKC / CTILE;
  __shared__ unsigned short Bt[2][CTILE * 256];   // 2 x 16KB

  const int tid = threadIdx.x;
  const int lane = tid & 63;
  const int w = tid >> 6;
  const int t0 = blockIdx.x * 128;
  const int k0 = blockIdx.y * CHUNKC;

  bf16x8 a[2][8];
  {
    const int rlo = lane & 15;
    const int khi = (lane >> 4) * 8;
#pragma unroll
    for (int rf = 0; rf < 2; ++rf) {
      const unsigned short* zr =
          zb + (size_t)(t0 + w * 32 + rf * 16 + rlo) * DDIM + khi;
#pragma unroll
      for (int kk = 0; kk < 8; ++kk)
        a[rf][kk] = *reinterpret_cast<const bf16x8*>(zr + kk * 32);
    }
  }

  float tr[2][4];
  float rm[2][4];
#pragma unroll
  for (int rf = 0; rf < 2; ++rf)
#pragma unroll
    for (int r = 0; r < 4; ++r) {
      rm[rf][r] = -1e30f;
      if (COLLECT)
        tr[rf][r] = funkey(gmx[t0 + w * 32 + rf * 16 + (lane >> 4) * 4 + r]) - DELTA;
    }

  const char* ebB = reinterpret_cast<const char*>(eb);
  const int sc = tid >> 3;
  const int ss = tid & 7;
  const int swz = (sc & 7) << 4;

  {
    const size_t gb = (size_t)(k0 + sc) * 512 + ss * 16;
    char* dst = reinterpret_cast<char*>(&Bt[0][0]) + sc * 512;
#pragma unroll
    for (int q = 0; q < 4; ++q) {
      const uint4 g = *reinterpret_cast<const uint4*>(ebB + gb + q * 128);
      *reinterpret_cast<uint4*>(dst + ((ss * 16 + q * 128) ^ swz)) = g;
    }
  }
  __syncthreads();

  const int rdlo = lane & 15;
  const int rdhi = (lane >> 4) * 16;
  uint4 g[4];

  for (int ct = 0; ct < NITC; ++ct) {
    if (ct + 1 < NITC) {
      const size_t gb = (size_t)(k0 + (ct + 1) * CTILE + sc) * 512 + ss * 16;
#pragma unroll
      for (int q = 0; q < 4; ++q)
        g[q] = *reinterpret_cast<const uint4*>(ebB + gb + q * 128);
    }

    f32x4 acc[2][2];
#pragma unroll
    for (int rf = 0; rf < 2; ++rf)
#pragma unroll
      for (int cf = 0; cf < 2; ++cf) acc[rf][cf] = (f32x4){0.f, 0.f, 0.f, 0.f};

    const char* buf = reinterpret_cast<const char*>(&Bt[ct & 1][0]);
#pragma unroll
    for (int kk = 0; kk < 8; ++kk) {
      const int off = (kk * 64 + rdhi) ^ ((rdlo & 7) << 4);
      const bf16x8 b0 = *reinterpret_cast<const bf16x8*>(buf + rdlo * 512 + off);
      const bf16x8 b1 = *reinterpret_cast<const bf16x8*>(buf + (16 + rdlo) * 512 + off);
      acc[0][0] = __builtin_amdgcn_mfma_f32_16x16x32_bf16(a[0][kk], b0, acc[0][0], 0, 0, 0);
      acc[1][0] = __builtin_amdgcn_mfma_f32_16x16x32_bf16(a[1][kk], b0, acc[1][0], 0, 0, 0);
      acc[0][1] = __builtin_amdgcn_mfma_f32_16x16x32_bf16(a[0][kk], b1, acc[0][1], 0, 0, 0);
      acc[1][1] = __builtin_amdgcn_mfma_f32_16x16x32_bf16(a[1][kk], b1, acc[1][1], 0, 0, 0);
    }

    if (!COLLECT) {
#pragma unroll
      for (int rf = 0; rf < 2; ++rf)
#pragma unroll
        for (int r = 0; r < 4; ++r)
          rm[rf][r] = fmaxf(rm[rf][r], fmaxf(acc[rf][0][r], acc[rf][1][r]));
    } else {
      const int kb = k0 + ct * CTILE;
#pragma unroll
      for (int rf = 0; rf < 2; ++rf) {
#pragma unroll
        for (int r = 0; r < 4; ++r) {
          const float th = tr[rf][r];
          if (acc[rf][0][r] >= th || acc[rf][1][r] >= th) {
            const int t = t0 + w * 32 + rf * 16 + (lane >> 4) * 4 + r;
            if (acc[rf][0][r] >= th) {
              const unsigned int o_ = atomicAdd(&cnt[t], 1u);
              if (o_ < CAP) lists[(size_t)t * CAP + o_] = (unsigned short)(kb + rdlo);
            }
            if (acc[rf][1][r] >= th) {
              const unsigned int o_ = atomicAdd(&cnt[t], 1u);
              if (o_ < CAP) lists[(size_t)t * CAP + o_] = (unsigned short)(kb + 16 + rdlo);
            }
          }
        }
      }
    }

    if (ct + 1 < NITC) {
      char* dst = reinterpret_cast<char*>(&Bt[(ct + 1) & 1][0]) + sc * 512;
#pragma unroll
      for (int q = 0; q < 4; ++q)
        *reinterpret_cast<uint4*>(dst + ((ss * 16 + q * 128) ^ swz)) = g[q];
    }
    __syncthreads();
  }

  if (!COLLECT) {
#pragma unroll
    for (int rf = 0; rf < 2; ++rf) {
#pragma unroll
      for (int r = 0; r < 4; ++r) {
        float v = rm[rf][r];
#pragma unroll
        for (int o = 1; o <= 8; o <<= 1) v = fmaxf(v, __shfl_xor(v, o));
        if ((lane & 15) == 0) {
          const int t = t0 + w * 32 + rf * 16 + (lane >> 4) * 4 + r;
          atomicMax(&gmx[t], fkey(v));
        }
      }
    }
  }
}

// ---------------- rescore + o0/loss + per-code count (NO o8 scatter) ----------------
__global__ __launch_bounds__(256) void k_rescore(
    const float* __restrict__ z, const float* __restrict__ emb,
    const float* __restrict__ an, const float* __restrict__ bn,
    const unsigned int* __restrict__ cnt, const unsigned short* __restrict__ lists,
    float* __restrict__ out_idx, int* __restrict__ idxi,
    float* __restrict__ o0, unsigned int* __restrict__ ucnt,
    float* __restrict__ scal) {
  const int w = threadIdx.x >> 6;
  const int lane = threadIdx.x & 63;
  const int t = blockIdx.x * 4 + w;

  const float4 z4 = *reinterpret_cast<const float4*>(z + (size_t)t * DDIM + lane * 4);
  const unsigned int nraw = cnt[t];
  const float aN = an[t];
  float bd = 3.4e38f;
  int bk = 0x7fffffff;

  if (nraw <= CAP) {
    const int n = (int)nraw;
    for (int c = 0; c < n; ++c) {
      const int k = (int)lists[(size_t)t * CAP + c];   // broadcast load
      const float4 e4 = *reinterpret_cast<const float4*>(emb + (size_t)k * DDIM + lane * 4);
      float p = z4.x * e4.x + z4.y * e4.y + z4.z * e4.z + z4.w * e4.w;
#pragma unroll
      for (int o = 32; o; o >>= 1) p += __shfl_xor(p, o);
      const float d = __fsub_rn(__fadd_rn(aN, bn[k]), __fmul_rn(2.0f, p));
      if (d < bd || (d == bd && k < bk)) { bd = d; bk = k; }
    }
  } else {
    // overflow fallback: cooperative full scan, 4-way unrolled (pipelined)
    for (int kb = 0; kb < KC; kb += 4) {
      float p0, p1, p2, p3;
      {
        const float4 e0 = *reinterpret_cast<const float4*>(emb + (size_t)(kb + 0) * DDIM + lane * 4);
        const float4 e1 = *reinterpret_cast<const float4*>(emb + (size_t)(kb + 1) * DDIM + lane * 4);
        const float4 e2 = *reinterpret_cast<const float4*>(emb + (size_t)(kb + 2) * DDIM + lane * 4);
        const float4 e3 = *reinterpret_cast<const float4*>(emb + (size_t)(kb + 3) * DDIM + lane * 4);
        p0 = z4.x * e0.x + z4.y * e0.y + z4.z * e0.z + z4.w * e0.w;
        p1 = z4.x * e1.x + z4.y * e1.y + z4.z * e1.z + z4.w * e1.w;
        p2 = z4.x * e2.x + z4.y * e2.y + z4.z * e2.z + z4.w * e2.w;
        p3 = z4.x * e3.x + z4.y * e3.y + z4.z * e3.z + z4.w * e3.w;
      }
#pragma unroll
      for (int o = 32; o; o >>= 1) {
        p0 += __shfl_xor(p0, o);
        p1 += __shfl_xor(p1, o);
        p2 += __shfl_xor(p2, o);
        p3 += __shfl_xor(p3, o);
      }
      const float d0 = __fsub_rn(__fadd_rn(aN, bn[kb + 0]), __fmul_rn(2.0f, p0));
      const float d1 = __fsub_rn(__fadd_rn(aN, bn[kb + 1]), __fmul_rn(2.0f, p1));
      const float d2 = __fsub_rn(__fadd_rn(aN, bn[kb + 2]), __fmul_rn(2.0f, p2));
      const float d3 = __fsub_rn(__fadd_rn(aN, bn[kb + 3]), __fmul_rn(2.0f, p3));
      if (d0 < bd) { bd = d0; bk = kb + 0; }
      if (d1 < bd) { bd = d1; bk = kb + 1; }
      if (d2 < bd) { bd = d2; bk = kb + 2; }
      if (d3 < bd) { bd = d3; bk = kb + 3; }
    }
  }

  if (lane == 0) {
    out_idx[t] = (float)bk;
    idxi[t] = bk;
    atomicAdd(&ucnt[bk], 1u);
  }

  // ---- o0 + loss epilogue (bk identical across lanes) ----
  const float4 ev = *reinterpret_cast<const float4*>(emb + (size_t)bk * DDIM + lane * 4);
  float4 o;
  o.x = __fadd_rn(z4.x, __fsub_rn(ev.x, z4.x));
  o.y = __fadd_rn(z4.y, __fsub_rn(ev.y, z4.y));
  o.z = __fadd_rn(z4.z, __fsub_rn(ev.z, z4.z));
  o.w = __fadd_rn(z4.w, __fsub_rn(ev.w, z4.w));
  *reinterpret_cast<float4*>(o0 + (size_t)t * DDIM + lane * 4) = o;
  const float dx = __fsub_rn(z4.x, ev.x);
  const float dy = __fsub_rn(z4.y, ev.y);
  const float dz = __fsub_rn(z4.z, ev.z);
  const float dw = __fsub_rn(z4.w, ev.w);
  float lsum = dx * dx + dy * dy + dz * dz + dw * dw;
#pragma unroll
  for (int o_ = 32; o_; o_ >>= 1) lsum += __shfl_down(lsum, o_);
  __shared__ float wsum[4];
  if (lane == 0) wsum[w] = lsum;
  __syncthreads();
  if (threadIdx.x == 0)
    atomicAdd(scal + 0, wsum[0] + wsum[1] + wsum[2] + wsum[3]);
}

// ---------------- exclusive prefix scan of per-code counts (1 block) ----------------
__global__ __launch_bounds__(256) void k_scan(const unsigned int* __restrict__ ucnt,
                                              unsigned int* __restrict__ base) {
  __shared__ unsigned int part[256];
  const int tid = threadIdx.x;
  unsigned int loc[32];
  unsigned int s = 0;
#pragma unroll
  for (int i = 0; i < 32; ++i) { loc[i] = s; s += ucnt[tid * 32 + i]; }
  part[tid] = s;
  __syncthreads();
  if (tid == 0) {
    unsigned int run = 0;
    for (int j = 0; j < 256; ++j) { const unsigned int v = part[j]; part[j] = run; run += v; }
  }
  __syncthreads();
  const unsigned int b = part[tid];
#pragma unroll
  for (int i = 0; i < 32; ++i) base[tid * 32 + i] = b + loc[i];
}

// ---------------- scatter token ids into per-code segments ----------------
__global__ __launch_bounds__(256) void k_scatter(const int* __restrict__ idxi,
                                                 const unsigned int* __restrict__ base,
                                                 unsigned int* __restrict__ fill,
                                                 unsigned short* __restrict__ tok) {
  const int t = blockIdx.x * 256 + threadIdx.x;
  const int k = idxi[t];
  const unsigned int p = atomicAdd(&fill[k], 1u);
  tok[base[k] + p] = (unsigned short)t;
}

// ---------------- gather v2: ONE BLOCK per code, 4 waves stride the cluster ----------------
// Imbalance-proof: worst cluster C -> C/4 pipelined iters/wave (2-deep prefetch).
// LDS 4-partial reduce, single non-atomic o8 row write. NO scalar atomics here
// (those live in the 32-block k_stats to avoid single-address storms).
__global__ __launch_bounds__(256) void k_gather(
    const float* __restrict__ z, const float* __restrict__ ema_w,
    const unsigned int* __restrict__ ucnt, const unsigned int* __restrict__ base,
    const unsigned short* __restrict__ tok,
    float* __restrict__ o8) {
  __shared__ float4 part[4][64];
  const int w = threadIdx.x >> 6;
  const int lane = threadIdx.x & 63;
  const int k = blockIdx.x;
  const unsigned int c = ucnt[k];
  const unsigned int b = base[k];

  float4 sum = {0.f, 0.f, 0.f, 0.f};
  unsigned int i = w;
  if (i < c) {
    int t = (int)tok[b + i];
    for (;;) {
      const unsigned int nx = i + 4;
      const bool has = nx < c;
      int tn = 0;
      if (has) tn = (int)tok[b + nx];          // prefetch next token id
      const float4 zv = *reinterpret_cast<const float4*>(z + (size_t)t * DDIM + lane * 4);
      sum.x += zv.x; sum.y += zv.y; sum.z += zv.z; sum.w += zv.w;
      if (!has) break;
      i = nx; t = tn;
    }
  }
  part[w][lane] = sum;
  __syncthreads();
  if (w == 0) {
    const float4 p1 = part[1][lane], p2 = part[2][lane], p3 = part[3][lane];
    sum.x += p1.x + p2.x + p3.x;
    sum.y += p1.y + p2.y + p3.y;
    sum.z += p1.z + p2.z + p3.z;
    sum.w += p1.w + p2.w + p3.w;
    const float4 ew = *reinterpret_cast<const float4*>(ema_w + (size_t)k * DDIM + lane * 4);
    float4 r;
    r.x = EMA * ew.x + ONE_M * sum.x;
    r.y = EMA * ew.y + ONE_M * sum.y;
    r.z = EMA * ew.z + ONE_M * sum.z;
    r.w = EMA * ew.w + ONE_M * sum.w;
    *reinterpret_cast<float4*>(o8 + (size_t)k * DDIM + lane * 4) = r;
  }
}

// ---------------- per-code stats from ucnt: block-reduced scalars ----------------
__global__ __launch_bounds__(256) void k_stats(const float* __restrict__ ecs_in,
                                               const float* __restrict__ cu_in,
                                               const unsigned int* __restrict__ ucnt,
                                               float* __restrict__ o7,
                                               float* __restrict__ o9,
                                               float* __restrict__ scal) {
  const int k = blockIdx.x * 256 + threadIdx.x;
  const int w = threadIdx.x >> 6;
  const int lane = threadIdx.x & 63;
  const float cc = (float)ucnt[k];
  const float raw = EMA * ecs_in[k] + ONE_M * cc;
  o7[k] = raw;
  const float ncu = __fadd_rn(cu_in[k], cc);
  o9[k] = ncu;
  const float p = cc * (1.0f / 16384.0f);
  float s0 = raw;
  float s1 = p * logf(p + 1e-10f);
  float s2 = ncu > 0.0f ? 1.0f : 0.0f;
#pragma unroll
  for (int o = 32; o; o >>= 1) {
    s0 += __shfl_down(s0, o);
    s1 += __shfl_down(s1, o);
    s2 += __shfl_down(s2, o);
  }
  __shared__ float w0[4], w1[4], w2[4];
  if (lane == 0) { w0[w] = s0; w1[w] = s1; w2[w] = s2; }
  __syncthreads();
  if (threadIdx.x == 0) {
    atomicAdd(scal + 1, w0[0] + w0[1] + w0[2] + w0[3]);
    atomicAdd(scal + 2, w1[0] + w1[1] + w1[2] + w1[3]);
    atomicAdd(scal + 3, w2[0] + w2[1] + w2[2] + w2[3]);
  }
}

// ---------------- fused: Laplace + emb update + scalar outputs ----------------
__global__ __launch_bounds__(256) void k_final(float* __restrict__ o7,
                                               const float* __restrict__ o8,
                                               const float* __restrict__ scal,
                                               float* __restrict__ o6,
                                               float* __restrict__ o2,
                                               float* __restrict__ o3,
                                               float* __restrict__ o4,
                                               float* __restrict__ o5) {
  const int lane = threadIdx.x & 63;
  const int k = blockIdx.x * 4 + (threadIdx.x >> 6);
  const float n = scal[1];
  const float raw = o7[k];
  const float sm = (raw + EPSF) / (n + KEPS) * n;
  if (lane == 0) o7[k] = sm;
  const float dnm = fmaxf(sm, EPSF);
  const size_t i = (size_t)k * DDIM + lane * 4;
  const float4 v = *reinterpret_cast<const float4*>(o8 + i);
  float4 r;
  r.x = v.x / dnm; r.y = v.y / dnm; r.z = v.z / dnm; r.w = v.w / dnm;
  *reinterpret_cast<float4*>(o6 + i) = r;
  if (blockIdx.x == 0 && threadIdx.x == 0) {
    const float m = scal[0] * (1.0f / 4194304.0f);
    o2[0] = 0.25f * m + m;
    o3[0] = expf(-scal[2]);
    o4[0] = scal[3] * (1.0f / 8192.0f);
    o5[0] = scal[3];
  }
}

extern "C" void kernel_launch(void* const* d_in, const int* in_sizes, int n_in,
                              void* d_out, int out_size, void* d_ws, size_t ws_size,
                              hipStream_t stream) {
  const float* z     = (const float*)d_in[0];
  const float* emb   = (const float*)d_in[1];
  const float* ecs   = (const float*)d_in[2];
  const float* ema_w = (const float*)d_in[3];
  const float* cu    = (const float*)d_in[4];

  float* out = (float*)d_out;
  float* o0 = out;
  float* o1 = o0 + 4194304;
  float* o2 = o1 + 16384;
  float* o3 = o2 + 1;
  float* o4 = o3 + 1;
  float* o5 = o4 + 1;
  float* o6 = o5 + 1;
  float* o7 = o6 + 2097152;
  float* o8 = o7 + 8192;
  float* o9 = o8 + 2097152;

  float* w    = (float*)d_ws;
  float* scal = w + SCAL_OFF;
  unsigned int* ucnt = (unsigned int*)(w + UCNT_OFF);
  unsigned int* fill = (unsigned int*)(w + FILL_OFF);
  unsigned int* cnt  = (unsigned int*)(w + CNT_OFF);
  unsigned int* gmx  = (unsigned int*)(w + GMX_OFF);
  float* an   = w + AN_OFF;
  float* bn   = w + BN_OFF;
  int*   idxi = (int*)(w + IDXI_OFF);
  unsigned int* base = (unsigned int*)(w + BASE_OFF);
  unsigned short* tok = (unsigned short*)(w + TOK_OFF);
  unsigned short* eb  = (unsigned short*)(w + EB_OFF);
  unsigned short* lists = (unsigned short*)(w + LISTS_OFF);
  // zb: bf16 copy of z in o0's first half (scratch until rescore overwrites)
  unsigned short* zb = (unsigned short*)o0;

  // one memset covers scal + ucnt + fill + cnt + gmx
  hipMemsetAsync(w, 0, (size_t)(GMX_OFF + TOKS) * sizeof(float), stream);

  k_conv<<<(KC + TOKS) / 4, 256, 0, stream>>>(emb, z, eb, zb, bn, an);

  // sample pass: codes 0..2047 (8 chunks of 256) -> gmx = per-token sample max
  k_screen<false><<<dim3(TOKS / 128, 8), 256, 0, stream>>>(zb, eb, gmx, cnt, lists);
  // collect pass: all 8192 codes (8 chunks of 1024); thr computed inline from gmx
  k_screen<true><<<dim3(TOKS / 128, 8), 256, 0, stream>>>(zb, eb, gmx, cnt, lists);

  // rescore (idx + o0 + loss + per-code counts; overwrites zb region of o0)
  k_rescore<<<TOKS / 4, 256, 0, stream>>>(z, emb, an, bn, cnt, lists,
                                          o1, idxi, o0, ucnt, scal);

  // inverted index: scan counts -> bases; scatter token ids; gather rows
  k_scan<<<1, 256, 0, stream>>>(ucnt, base);
  k_scatter<<<TOKS / 256, 256, 0, stream>>>(idxi, base, fill, tok);
  k_gather<<<KC, 256, 0, stream>>>(z, ema_w, ucnt, base, tok, o8);
  k_stats<<<KC / 256, 256, 0, stream>>>(ecs, cu, ucnt, o7, o9, scal);

  k_final<<<KC / 4, 256, 0, stream>>>(o7, o8, scal, o6, o2, o3, o4, o5);
}